// Round 1
// baseline (200.292 us; speedup 1.0000x reference)
//
#include <hip/hip_runtime.h>
#include <hip/hip_bf16.h>

#define NUM_HEADS 4
#define HEAD_DIM 64
#define HD 256
#define QD 256
#define VD 256
#define B_SZ 32
#define N_NODES 8192
#define NEG_SLOPE 0.2f

typedef short bf16x8 __attribute__((ext_vector_type(8)));
typedef unsigned short u16x8 __attribute__((ext_vector_type(8)));
typedef float f32x4 __attribute__((ext_vector_type(4)));

static __device__ __forceinline__ unsigned short f2bf(float f) {
    __hip_bfloat16 h = __float2bfloat16(f);
    return *reinterpret_cast<unsigned short*>(&h);
}

// ---------------------------------------------------------------------------
// Kernel 1: prep
//  blocks 0..31   : hqb[b][col] = query[b]@Wq[:,col] + 2*bq[col]
//  blocks 32..63  : pack Wq -> bf16 fragment order:
//                   WqP[kstep*8192 + col*32 + g*8 + j] = bf16(Wq[kstep*32+g*8+j][col])
//  blocks 64..95  : zero p[32*4*256]
// ---------------------------------------------------------------------------
__global__ __launch_bounds__(256)
void prep_kernel(const float* __restrict__ query,
                 const float* __restrict__ Wq,
                 const float* __restrict__ bq,
                 unsigned short* __restrict__ WqP,
                 float* __restrict__ hqb,
                 float* __restrict__ p) {
    int blk = blockIdx.x;
    int tid = threadIdx.x;
    if (blk < 32) {
        int b = blk, col = tid;
        float acc = 2.0f * bq[col];
#pragma unroll 4
        for (int k = 0; k < QD; ++k)
            acc += query[b * QD + k] * Wq[k * HD + col];
        hqb[b * HD + col] = acc;
    } else if (blk < 64) {
        int idx = blk - 32;
        int kstep = idx >> 2, g = idx & 3;
        int col = tid;
        u16x8 v;
#pragma unroll
        for (int j = 0; j < 8; ++j)
            v[j] = f2bf(Wq[(kstep * 32 + g * 8 + j) * HD + col]);
        *reinterpret_cast<u16x8*>(WqP + kstep * 8192 + col * 32 + g * 8) = v;
    } else {
        int idx = (blk - 64) * 1024 + tid * 4;
        float4 z = {0.f, 0.f, 0.f, 0.f};
        *reinterpret_cast<float4*>(p + idx) = z;
    }
}

// ---------------------------------------------------------------------------
// Kernel 2: score pass. Block = 64 key rows of one b, 4 waves, wave w = head w.
// Each wave: 64x64 C-tile (4x4 frags of 16x16), K-loop 8 steps of 32 over QD.
// Epilogue: s[b][h][n] = sum_d a[d]*leaky_relu(hk + hqb)
// ---------------------------------------------------------------------------
__global__ __launch_bounds__(256)
void score_kernel(const float* __restrict__ key,
                  const unsigned short* __restrict__ WqP,
                  const float* __restrict__ hqb,
                  const float* __restrict__ avec,
                  float* __restrict__ s) {
    __shared__ __align__(16) unsigned short kt[64][40];  // +8 ushort pad: 80B row stride

    int bid = blockIdx.x;
    int b = bid >> 7;
    int nt = bid & 127;
    int n0 = nt * 64;
    int tid = threadIdx.x;
    int w = tid >> 6;            // wave index == head
    int lane = tid & 63;
    int col16 = lane & 15;
    int g = lane >> 4;

    f32x4 acc[4][4];
#pragma unroll
    for (int i = 0; i < 4; ++i)
#pragma unroll
        for (int j = 0; j < 4; ++j)
            acc[i][j] = (f32x4){0.f, 0.f, 0.f, 0.f};

    int srow = tid >> 2;          // 0..63
    int skc = (tid & 3) * 8;      // 0,8,16,24
    const float* kbase = key + ((size_t)(b * N_NODES + n0 + srow)) * QD + skc;

    for (int ks = 0; ks < 8; ++ks) {
        float4 f0 = *reinterpret_cast<const float4*>(kbase + ks * 32);
        float4 f1 = *reinterpret_cast<const float4*>(kbase + ks * 32 + 4);
        __syncthreads();   // previous iteration's ds_reads done
        u16x8 cv;
        cv[0] = f2bf(f0.x); cv[1] = f2bf(f0.y); cv[2] = f2bf(f0.z); cv[3] = f2bf(f0.w);
        cv[4] = f2bf(f1.x); cv[5] = f2bf(f1.y); cv[6] = f2bf(f1.z); cv[7] = f2bf(f1.w);
        *reinterpret_cast<u16x8*>(&kt[srow][skc]) = cv;
        __syncthreads();   // tile visible

        bf16x8 afr[4], bfr[4];
#pragma unroll
        for (int rt = 0; rt < 4; ++rt)
            afr[rt] = *reinterpret_cast<const bf16x8*>(&kt[rt * 16 + col16][g * 8]);
        const unsigned short* wp = WqP + ks * 8192 + (w * 64) * 32 + g * 8;
#pragma unroll
        for (int ct = 0; ct < 4; ++ct)
            bfr[ct] = *reinterpret_cast<const bf16x8*>(wp + (ct * 16 + col16) * 32);
#pragma unroll
        for (int rt = 0; rt < 4; ++rt)
#pragma unroll
            for (int ct = 0; ct < 4; ++ct)
                acc[rt][ct] = __builtin_amdgcn_mfma_f32_16x16x32_bf16(
                    afr[rt], bfr[ct], acc[rt][ct], 0, 0, 0);
    }

    // epilogue: leaky_relu + dot with a + reduce over 64 cols of this head
    float hq_[4], av[4];
#pragma unroll
    for (int ct = 0; ct < 4; ++ct) {
        int col = w * 64 + ct * 16 + col16;
        hq_[ct] = hqb[b * HD + col];
        av[ct] = avec[ct * 16 + col16];
    }
#pragma unroll
    for (int rt = 0; rt < 4; ++rt) {
        float part[4] = {0.f, 0.f, 0.f, 0.f};
#pragma unroll
        for (int ct = 0; ct < 4; ++ct) {
#pragma unroll
            for (int r = 0; r < 4; ++r) {
                float pre = acc[rt][ct][r] + hq_[ct];
                float t = pre > 0.f ? pre : NEG_SLOPE * pre;
                part[r] += av[ct] * t;
            }
        }
#pragma unroll
        for (int off = 1; off < 16; off <<= 1)
#pragma unroll
            for (int r = 0; r < 4; ++r)
                part[r] += __shfl_xor(part[r], off, 64);
        if (col16 == 0) {
            int rowbase = n0 + rt * 16 + g * 4;
            float* sp = s + ((size_t)(b * NUM_HEADS + w)) * N_NODES + rowbase;
#pragma unroll
            for (int r = 0; r < 4; ++r) sp[r] = part[r];
        }
    }
}

// ---------------------------------------------------------------------------
// Kernel 3: softmax over n per (b,h). Writes e to d_out (B,N,H layout) and a
// compact [b][h][n] copy for the PV pass.
// ---------------------------------------------------------------------------
__global__ __launch_bounds__(256)
void softmax_kernel(const float* __restrict__ s,
                    float* __restrict__ e_out,
                    float* __restrict__ e2) {
    int bh = blockIdx.x;
    int b = bh >> 2, h = bh & 3;
    int tid = threadIdx.x;
    const float* sp = s + (size_t)bh * N_NODES;

    float v[32];
#pragma unroll
    for (int c = 0; c < 8; ++c) {
        float4 f = *reinterpret_cast<const float4*>(sp + c * 1024 + tid * 4);
        v[c * 4 + 0] = f.x; v[c * 4 + 1] = f.y; v[c * 4 + 2] = f.z; v[c * 4 + 3] = f.w;
    }
    float mx = -1e30f;
#pragma unroll
    for (int i = 0; i < 32; ++i) mx = fmaxf(mx, v[i]);
#pragma unroll
    for (int off = 1; off < 64; off <<= 1) mx = fmaxf(mx, __shfl_xor(mx, off, 64));

    __shared__ float redmx[4];
    __shared__ float redsum[4];
    int wv = tid >> 6, lane = tid & 63;
    if (lane == 0) redmx[wv] = mx;
    __syncthreads();
    mx = fmaxf(fmaxf(redmx[0], redmx[1]), fmaxf(redmx[2], redmx[3]));

    float sum = 0.f;
#pragma unroll
    for (int i = 0; i < 32; ++i) { v[i] = expf(v[i] - mx); sum += v[i]; }
#pragma unroll
    for (int off = 1; off < 64; off <<= 1) sum += __shfl_xor(sum, off, 64);
    if (lane == 0) redsum[wv] = sum;
    __syncthreads();
    sum = redsum[0] + redsum[1] + redsum[2] + redsum[3];
    float inv = 1.0f / sum;

#pragma unroll
    for (int c = 0; c < 8; ++c) {
        int n = c * 1024 + tid * 4;
        float4 ev;
        ev.x = v[c * 4 + 0] * inv; ev.y = v[c * 4 + 1] * inv;
        ev.z = v[c * 4 + 2] * inv; ev.w = v[c * 4 + 3] * inv;
        *reinterpret_cast<float4*>(e2 + (size_t)bh * N_NODES + n) = ev;
        float* eo = e_out + ((size_t)(b * N_NODES + n)) * NUM_HEADS + h;
        eo[0] = ev.x; eo[4] = ev.y; eo[8] = ev.z; eo[12] = ev.w;
    }
}

// ---------------------------------------------------------------------------
// Kernel 4: p[b][h][k] = sum_n e[b][h][n] * value[b][n][k]   (atomic partials)
// ---------------------------------------------------------------------------
__global__ __launch_bounds__(256)
void pv_kernel(const float* __restrict__ value,
               const float* __restrict__ e2,
               float* __restrict__ p) {
    int bid = blockIdx.x;
    int b = bid >> 6, ch = bid & 63;
    int n0 = ch * 128;
    int tid = threadIdx.x;
    int k = tid;

    __shared__ float es[4][128];
    for (int i = tid; i < 512; i += 256) {
        int h = i >> 7, n = i & 127;
        es[h][n] = e2[((size_t)(b * 4 + h)) * N_NODES + n0 + n];
    }
    __syncthreads();

    float a0 = 0.f, a1 = 0.f, a2 = 0.f, a3 = 0.f;
    const float* vp = value + ((size_t)(b * N_NODES + n0)) * VD + k;
#pragma unroll 4
    for (int n = 0; n < 128; ++n) {
        float v = vp[(size_t)n * VD];
        a0 += es[0][n] * v;
        a1 += es[1][n] * v;
        a2 += es[2][n] * v;
        a3 += es[3][n] * v;
    }
    float* pp = p + (size_t)b * 4 * 256;
    atomicAdd(pp + 0 * 256 + k, a0);
    atomicAdd(pp + 1 * 256 + k, a1);
    atomicAdd(pp + 2 * 256 + k, a2);
    atomicAdd(pp + 3 * 256 + k, a3);
}

// ---------------------------------------------------------------------------
// Kernel 5: h_prime[b][h*64+d] = relu( p[b][h] @ Wv[:, h*64+d] + bv[h*64+d] )
// ---------------------------------------------------------------------------
__global__ __launch_bounds__(64)
void out_kernel(const float* __restrict__ p,
                const float* __restrict__ Wv,
                const float* __restrict__ bv,
                float* __restrict__ hout) {
    int bh = blockIdx.x;
    int b = bh >> 2, h = bh & 3;
    int d = threadIdx.x;
    const float* pp = p + (size_t)bh * 256;
    float acc = bv[h * 64 + d];
#pragma unroll 4
    for (int k = 0; k < 256; ++k)
        acc += pp[k] * Wv[k * HD + h * 64 + d];
    hout[b * HD + h * 64 + d] = fmaxf(acc, 0.f);
}

extern "C" void kernel_launch(void* const* d_in, const int* in_sizes, int n_in,
                              void* d_out, int out_size, void* d_ws, size_t ws_size,
                              hipStream_t stream) {
    const float* query = (const float*)d_in[0];
    const float* key   = (const float*)d_in[1];
    const float* value = (const float*)d_in[2];
    const float* Wq    = (const float*)d_in[3];
    const float* bq    = (const float*)d_in[4];
    const float* Wv    = (const float*)d_in[5];
    const float* bv    = (const float*)d_in[6];
    const float* avec  = (const float*)d_in[7];
    float* out = (float*)d_out;

    char* ws = (char*)d_ws;
    unsigned short* WqP = (unsigned short*)ws;              // 131072 B
    float* hqb = (float*)(ws + 131072);                     // 32768 B
    float* p   = (float*)(ws + 131072 + 32768);             // 131072 B
    float* s   = (float*)(ws + 294912);                     // 4 MB
    float* e2  = (float*)(ws + 294912 + 4194304);           // 4 MB

    prep_kernel<<<96, 256, 0, stream>>>(query, Wq, bq, WqP, hqb, p);
    score_kernel<<<B_SZ * (N_NODES / 64), 256, 0, stream>>>(key, WqP, hqb, avec, s);
    softmax_kernel<<<B_SZ * NUM_HEADS, 256, 0, stream>>>(s, out + B_SZ * HD, e2);
    pv_kernel<<<B_SZ * 64, 256, 0, stream>>>(value, e2, p);
    out_kernel<<<B_SZ * NUM_HEADS, 64, 0, stream>>>(p, Wv, bv, out);
}